// Round 1
// 714.215 us; speedup vs baseline: 1.3642x; 1.3642x over previous
//
#include <hip/hip_runtime.h>

// MHA fused forward: x = (softmax(split(QWq^T+bq) @ split(KWk^T+bk)^T / 8, mask) @ split(VWv^T+bv)) merged @ Wo^T + bo
// B=4 N=1024 D=1024 H=16 DH=64.  Outputs: x [4,1024,1024] fp32 then weights [4,16,1024,1024] fp32.

#define SEQ   1024
#define D_DIM 1024
#define HEADS 16
#define DHEAD 64
#define BATCH 4

typedef __attribute__((ext_vector_type(8))) short bhalf8;
typedef __attribute__((ext_vector_type(4))) float floatx4;

static __device__ __forceinline__ unsigned short f2b(float f) {
    // fp32 -> bf16 round-to-nearest-even (inputs are finite randoms; NaN path not needed)
    unsigned int u = __float_as_uint(f);
    u += 0x7FFFu + ((u >> 16) & 1u);
    return (unsigned short)(u >> 16);
}

// ---------------------------------------------------------------------------
// Mask dtype probe. bool mask may arrive as uint8, int32 or fp32. Byte mode
// (10% ones): P(a word is not in {0,1,0x3F800000}) ~= 0.27, so 16K words give
// miss prob 0.73^16384 ~ 0. Read 64KB as uint4, reduce, single block writes flag.
// ---------------------------------------------------------------------------
__global__ __launch_bounds__(256) void detect_mask_kernel(const uint4* __restrict__ m,
                                                          int* __restrict__ flag) {
    __shared__ int found;
    if (threadIdx.x == 0) found = 0;
    __syncthreads();
    unsigned int bad = 0;
#pragma unroll
    for (int i = 0; i < 16; ++i) {
        uint4 w = m[threadIdx.x + i * 256];  // 4096 uint4 = 64KB
        unsigned int a = w.x, b = w.y, c = w.z, d = w.w;
        bad |= (a != 0u && a != 1u && a != 0x3F800000u);
        bad |= (b != 0u && b != 1u && b != 0x3F800000u);
        bad |= (c != 0u && c != 1u && c != 0x3F800000u);
        bad |= (d != 0u && d != 1u && d != 0x3F800000u);
    }
    if (bad) atomicOr(&found, 1);
    __syncthreads();
    if (threadIdx.x == 0) *flag = found;  // 1 = byte elements, 0 = 4-byte elements
}

// ---------------------------------------------------------------------------
// Pack mask into bit array: bits[(bh*SEQ+row)*32 + col/32], bit col%32.
// 64MB bytes -> 8MB bits, read once, coalesced. Replaces per-j ballot rounds
// + cold scattered byte loads inside the attention kernel.
// One thread = one output word = 32 mask elements. 2M words -> grid 8192.
// ---------------------------------------------------------------------------
__global__ __launch_bounds__(256) void mask_pack(const void* __restrict__ mask,
                                                 const int* __restrict__ mflagp,
                                                 unsigned int* __restrict__ bits) {
    const size_t idx = (size_t)blockIdx.x * 256 + threadIdx.x;
    unsigned int w = 0;
    if (*mflagp) {
        const uint4* p = (const uint4*)mask + idx * 2;  // 32 bytes
        uint4 a = p[0], b = p[1];
        unsigned int d[8] = {a.x, a.y, a.z, a.w, b.x, b.y, b.z, b.w};
#pragma unroll
        for (int i = 0; i < 8; ++i) {
            unsigned int x = d[i];
            w |= (((x & 0x000000FFu) != 0u) ? 1u : 0u) << (i * 4 + 0);
            w |= (((x & 0x0000FF00u) != 0u) ? 1u : 0u) << (i * 4 + 1);
            w |= (((x & 0x00FF0000u) != 0u) ? 1u : 0u) << (i * 4 + 2);
            w |= (((x & 0xFF000000u) != 0u) ? 1u : 0u) << (i * 4 + 3);
        }
    } else {
        const uint4* p = (const uint4*)mask + idx * 8;  // 128 bytes
#pragma unroll
        for (int i = 0; i < 8; ++i) {
            uint4 a = p[i];
            w |= (a.x ? 1u : 0u) << (i * 4 + 0);
            w |= (a.y ? 1u : 0u) << (i * 4 + 1);
            w |= (a.z ? 1u : 0u) << (i * 4 + 2);
            w |= (a.w ? 1u : 0u) << (i * 4 + 3);
        }
    }
    bits[idx] = w;
}

// ---------------------------------------------------------------------------
// GEMM: Out[m, n] = sum_k A[m, k] * W[n, k] + bias[n]   (torch Linear, W row-major [out,in])
// M=4096, N=1024, K=1024. 128x128 tile, BK=64, 4 waves (2x2), 4x4 MFMA tiles/wave.
// AMODE 0: A fp32 (convert to bf16 during staging); AMODE 1: A bf16.
// OMODE 0: write bf16 scattered to [b,h,n,dh] (+bias); OMODE 1: write fp32 row-major (+bias).
// ---------------------------------------------------------------------------
template <int AMODE, int OMODE>
__global__ __launch_bounds__(256) void gemm_bt(const void* __restrict__ Aptr,
                                               const float* __restrict__ W,
                                               const float* __restrict__ bias,
                                               void* __restrict__ Out) {
    __shared__ unsigned short Al[128 * 72];  // +8 pad: row stride 144B -> 2-way bank alias (free)
    __shared__ unsigned short Bl[128 * 72];

    const int tid = threadIdx.x;
    const int lane = tid & 63, wid = tid >> 6;
    const int lr = lane & 15, lq = lane >> 4;
    const int wm = (wid & 1) * 64, wn = (wid >> 1) * 64;
    const int rowBase = blockIdx.y * 128;
    const int colBase = blockIdx.x * 128;

    floatx4 acc[4][4];
    for (int mi = 0; mi < 4; ++mi)
        for (int ni = 0; ni < 4; ++ni)
            for (int r = 0; r < 4; ++r) acc[mi][ni][r] = 0.f;

    for (int k0 = 0; k0 < D_DIM; k0 += 64) {
        if (AMODE == 0) {
            const float* A = (const float*)Aptr;
            for (int i = 0; i < 8; ++i) {
                int id = tid + i * 256;          // 2048 float4 chunks = 128 rows x 16
                int r = id >> 4, c4 = id & 15;
                float4 f = *(const float4*)&A[(size_t)(rowBase + r) * D_DIM + k0 + c4 * 4];
                ushort4 h;
                h.x = f2b(f.x); h.y = f2b(f.y); h.z = f2b(f.z); h.w = f2b(f.w);
                *(ushort4*)&Al[r * 72 + c4 * 4] = h;
            }
        } else {
            const unsigned short* A = (const unsigned short*)Aptr;
            for (int i = 0; i < 4; ++i) {
                int id = tid + i * 256;          // 1024 bf16x8 chunks = 128 rows x 8
                int r = id >> 3, c8 = id & 7;
                *(uint4*)&Al[r * 72 + c8 * 8] =
                    *(const uint4*)&A[(size_t)(rowBase + r) * D_DIM + k0 + c8 * 8];
            }
        }
        for (int i = 0; i < 8; ++i) {
            int id = tid + i * 256;
            int r = id >> 4, c4 = id & 15;
            float4 f = *(const float4*)&W[(size_t)(colBase + r) * D_DIM + k0 + c4 * 4];
            ushort4 h;
            h.x = f2b(f.x); h.y = f2b(f.y); h.z = f2b(f.z); h.w = f2b(f.w);
            *(ushort4*)&Bl[r * 72 + c4 * 4] = h;
        }
        __syncthreads();
        for (int ks = 0; ks < 2; ++ks) {
            bhalf8 af[4], bfr[4];
            for (int mi = 0; mi < 4; ++mi)
                af[mi] = *(const bhalf8*)&Al[(wm + mi * 16 + lr) * 72 + ks * 32 + lq * 8];
            for (int ni = 0; ni < 4; ++ni)
                bfr[ni] = *(const bhalf8*)&Bl[(wn + ni * 16 + lr) * 72 + ks * 32 + lq * 8];
            for (int mi = 0; mi < 4; ++mi)
                for (int ni = 0; ni < 4; ++ni)
                    acc[mi][ni] = __builtin_amdgcn_mfma_f32_16x16x32_bf16(af[mi], bfr[ni],
                                                                          acc[mi][ni], 0, 0, 0);
        }
        __syncthreads();
    }

    // Epilogue. C/D layout (verified m89/m91): col = lane&15, row = (lane>>4)*4 + reg.
    for (int mi = 0; mi < 4; ++mi) {
        for (int ni = 0; ni < 4; ++ni) {
            int col = colBase + wn + ni * 16 + lr;
            float bv = bias[col];
            for (int r = 0; r < 4; ++r) {
                int m = rowBase + wm + mi * 16 + lq * 4 + r;
                float v = acc[mi][ni][r] + bv;
                if (OMODE == 0) {
                    unsigned short* o = (unsigned short*)Out;
                    int b = m >> 10, n = m & 1023, h = col >> 6, dh = col & 63;
                    o[(((size_t)(b * HEADS + h)) << 16) + (n << 6) + dh] = f2b(v);
                } else {
                    float* o = (float*)Out;
                    o[(size_t)m * D_DIM + col] = v;
                }
            }
        }
    }
}

// ---------------------------------------------------------------------------
// Attention: one block = one (b,h) and a 64-row q tile. Two-pass softmax,
// restructured for latency hiding:
//  - mask bits staged once per block from the packed bit array (no ballots)
//  - per-LANE online (m,l) in pass 1; single cross-lane merge at the end
//    (removes 2 shuffle trees per j-iteration)
//  - K (and V in pass 2) prefetched into registers one tile ahead (T14)
//  - XOR-swizzled unpadded LDS tiles: conflict-free ds_read_b128, and
//    LDS = 40KB exactly -> 4 blocks/CU (was 44KB -> 3)
//  - 1-D grid with XCD-grouped decode: all 16 q-tiles of a (b,h) share an
//    XCD L2 for K/V re-reads
// LDS ushort index swizzle: addr(row,col) = row*64 + (col ^ ((row&7)<<3));
// 16B-group form: row*64 + ((g ^ (row&7))<<3). Write side uses the identical
// involution, so reads of group g return original cols g*8..g*8+7.
// ---------------------------------------------------------------------------
__global__ __launch_bounds__(256, 4) void attn_kernel(const unsigned short* __restrict__ qh,
                                                      const unsigned short* __restrict__ kh,
                                                      const unsigned short* __restrict__ vh,
                                                      const unsigned int* __restrict__ bits,
                                                      float* __restrict__ wout,
                                                      unsigned short* __restrict__ attnb) {
    __shared__ unsigned short ql[64 * 64];
    __shared__ unsigned short kl[64 * 64];
    __shared__ unsigned short vtl[64 * 64];
    __shared__ unsigned short pl[64 * 64];
    __shared__ unsigned int maskw[64 * 32];  // 64 rows x 1024 bits

    const int tid = threadIdx.x;
    const int lane = tid & 63, wid = tid >> 6;
    const int lr = lane & 15, lq = lane >> 4;

    // XCD-grouped decode: same-bh tiles share wg%8 -> same XCD (round-robin heuristic)
    const int wg = blockIdx.x;
    const int xcd = wg & 7, tt = wg >> 3;
    const int bh = ((tt >> 4) << 3) | xcd;   // 0..63
    const int row0 = (tt & 15) << 6;

    const size_t hoff = (size_t)bh << 16;  // *SEQ*DHEAD
    const unsigned short* qp = qh + hoff;
    const unsigned short* kp = kh + hoff;
    const unsigned short* vp = vh + hoff;

    // ---- one-time staging: q tile (swizzled) + mask bits (8KB, coalesced) ----
#pragma unroll
    for (int i = 0; i < 2; ++i) {
        int id = tid + i * 256;
        int r = id >> 3, c8 = id & 7;
        *(uint4*)&ql[r * 64 + ((c8 ^ (r & 7)) << 3)] =
            *(const uint4*)&qp[((size_t)(row0 + r) << 6) + c8 * 8];
    }
    {
        const unsigned int* src = bits + ((size_t)bh * SEQ + row0) * 32;
#pragma unroll
        for (int i = 0; i < 2; ++i) {
            int id = tid + i * 256;  // 512 uint4 = 2048 words
            *(uint4*)&maskw[id * 4] = *(const uint4*)&src[id * 4];
        }
    }

    uint4 kreg0, kreg1, vreg0, vreg1;
#define LOADK(j)                                                                          \
    {                                                                                     \
        kreg0 = *(const uint4*)&kp[((size_t)(((j) << 6) + (tid >> 3)) << 6) + (tid & 7) * 8];        \
        kreg1 = *(const uint4*)&kp[((size_t)(((j) << 6) + ((tid + 256) >> 3)) << 6) + (tid & 7) * 8]; \
    }
#define STOREK                                                                  \
    {                                                                           \
        int r0 = tid >> 3, c0 = tid & 7, r1 = (tid + 256) >> 3;                 \
        *(uint4*)&kl[r0 * 64 + ((c0 ^ (r0 & 7)) << 3)] = kreg0;                 \
        *(uint4*)&kl[r1 * 64 + ((c0 ^ (r1 & 7)) << 3)] = kreg1;                 \
    }
#define LOADV(j)                                                                          \
    {                                                                                     \
        vreg0 = *(const uint4*)&vp[((size_t)(((j) << 6) + (tid & 63)) << 6) + ((tid >> 6) * 8)];      \
        vreg1 = *(const uint4*)&vp[((size_t)(((j) << 6) + (tid & 63)) << 6) + ((tid >> 6) * 8 + 32)]; \
    }
#define STOREV                                                                  \
    {                                                                           \
        int n0 = tid & 63, d0 = (tid >> 6) * 8, d1 = d0 + 32;                   \
        const unsigned short* e0 = (const unsigned short*)&vreg0;               \
        const unsigned short* e1 = (const unsigned short*)&vreg1;               \
        _Pragma("unroll") for (int t = 0; t < 8; ++t) {                         \
            vtl[(d0 + t) * 64 + (n0 ^ (t << 3))] = e0[t];                       \
            vtl[(d1 + t) * 64 + (n0 ^ (t << 3))] = e1[t];                       \
        }                                                                       \
    }

    // ---- pass 1: per-lane online (m,l); merge across lanes once at the end ----
    float m_l[4], l_l[4];
#pragma unroll
    for (int r = 0; r < 4; ++r) { m_l[r] = -3e38f; l_l[r] = 0.f; }

    LOADK(0);
    for (int j = 0; j < 16; ++j) {
        __syncthreads();           // prior iter's kl reads done
        STOREK;
        if (j < 15) LOADK(j + 1);  // prefetch hides HBM/L2 latency under compute
        __syncthreads();

        floatx4 sacc[4];
#pragma unroll
        for (int c = 0; c < 4; ++c)
#pragma unroll
            for (int r = 0; r < 4; ++r) sacc[c][r] = 0.f;
#pragma unroll
        for (int ks = 0; ks < 2; ++ks) {
            int arow = wid * 16 + lr;
            bhalf8 a = *(const bhalf8*)&ql[arow * 64 + (((ks * 4 + lq) ^ (lr & 7)) << 3)];
#pragma unroll
            for (int c = 0; c < 4; ++c) {
                int brow = c * 16 + lr;
                bhalf8 bb = *(const bhalf8*)&kl[brow * 64 + (((ks * 4 + lq) ^ (lr & 7)) << 3)];
                sacc[c] = __builtin_amdgcn_mfma_f32_16x16x32_bf16(a, bb, sacc[c], 0, 0, 0);
            }
        }
        unsigned int w0[4], w1[4];
#pragma unroll
        for (int r = 0; r < 4; ++r) {
            int row = wid * 16 + lq * 4 + r;
            w0[r] = maskw[row * 32 + j * 2];
            w1[r] = maskw[row * 32 + j * 2 + 1];
        }
#pragma unroll
        for (int c = 0; c < 4; ++c) {
            int sh = lr + ((c & 1) << 4);
#pragma unroll
            for (int r = 0; r < 4; ++r) {
                unsigned int w = (c >> 1) ? w1[r] : w0[r];
                float s = sacc[c][r] * 0.125f;  // /sqrt(64)
                sacc[c][r] = ((w >> sh) & 1u) ? -1e10f : s;
            }
        }
#pragma unroll
        for (int r = 0; r < 4; ++r) {
            float mx = fmaxf(fmaxf(sacc[0][r], sacc[1][r]), fmaxf(sacc[2][r], sacc[3][r]));
            float mn = fmaxf(m_l[r], mx);
            float sv = __expf(sacc[0][r] - mn) + __expf(sacc[1][r] - mn) +
                       __expf(sacc[2][r] - mn) + __expf(sacc[3][r] - mn);
            l_l[r] = l_l[r] * __expf(m_l[r] - mn) + sv;
            m_l[r] = mn;
        }
    }
    // merge (m,l) across the 16 lanes sharing each row (xor stays within lq group)
#pragma unroll
    for (int o = 1; o < 16; o <<= 1) {
#pragma unroll
        for (int r = 0; r < 4; ++r) {
            float mo = __shfl_xor(m_l[r], o);
            float lo = __shfl_xor(l_l[r], o);
            float mn = fmaxf(m_l[r], mo);
            l_l[r] = l_l[r] * __expf(m_l[r] - mn) + lo * __expf(mo - mn);
            m_l[r] = mn;
        }
    }
    float invl[4];
#pragma unroll
    for (int r = 0; r < 4; ++r) invl[r] = 1.f / l_l[r];

    // ---- pass 2: weights out + P@V (recompute S; K/V prefetched) ----
    floatx4 oacc[4];
#pragma unroll
    for (int c = 0; c < 4; ++c)
#pragma unroll
        for (int r = 0; r < 4; ++r) oacc[c][r] = 0.f;
    const size_t wrowbase = ((size_t)bh * SEQ + row0) * SEQ;

    LOADK(0);
    LOADV(0);
    for (int j = 0; j < 16; ++j) {
        __syncthreads();
        STOREK;
        STOREV;
        if (j < 15) { LOADK(j + 1); LOADV(j + 1); }
        __syncthreads();

        floatx4 sacc[4];
#pragma unroll
        for (int c = 0; c < 4; ++c)
#pragma unroll
            for (int r = 0; r < 4; ++r) sacc[c][r] = 0.f;
#pragma unroll
        for (int ks = 0; ks < 2; ++ks) {
            int arow = wid * 16 + lr;
            bhalf8 a = *(const bhalf8*)&ql[arow * 64 + (((ks * 4 + lq) ^ (lr & 7)) << 3)];
#pragma unroll
            for (int c = 0; c < 4; ++c) {
                int brow = c * 16 + lr;
                bhalf8 bb = *(const bhalf8*)&kl[brow * 64 + (((ks * 4 + lq) ^ (lr & 7)) << 3)];
                sacc[c] = __builtin_amdgcn_mfma_f32_16x16x32_bf16(a, bb, sacc[c], 0, 0, 0);
            }
        }
        unsigned int w0[4], w1[4];
#pragma unroll
        for (int r = 0; r < 4; ++r) {
            int row = wid * 16 + lq * 4 + r;
            w0[r] = maskw[row * 32 + j * 2];
            w1[r] = maskw[row * 32 + j * 2 + 1];
        }
#pragma unroll
        for (int c = 0; c < 4; ++c) {
            int sh = lr + ((c & 1) << 4);
            int col = (j << 6) + c * 16 + lr;
#pragma unroll
            for (int r = 0; r < 4; ++r) {
                unsigned int w = (c >> 1) ? w1[r] : w0[r];
                int row = wid * 16 + lq * 4 + r;
                float s = sacc[c][r] * 0.125f;
                if ((w >> sh) & 1u) s = -1e10f;
                float p = __expf(s - m_l[r]) * invl[r];
                wout[wrowbase + (size_t)row * SEQ + col] = p;
                // same wave writes & reads its 16-row strip; swizzled scalar store
                pl[row * 64 + ((c * 16 + lr) ^ ((row & 7) << 3))] = f2b(p);
            }
        }
#pragma unroll
        for (int ks = 0; ks < 2; ++ks) {
            int arow = wid * 16 + lr;
            bhalf8 a = *(const bhalf8*)&pl[arow * 64 + (((ks * 4 + lq) ^ (lr & 7)) << 3)];
#pragma unroll
            for (int c = 0; c < 4; ++c) {
                int brow = c * 16 + lr;
                bhalf8 bb = *(const bhalf8*)&vtl[brow * 64 + (((ks * 4 + lq) ^ (lr & 7)) << 3)];
                oacc[c] = __builtin_amdgcn_mfma_f32_16x16x32_bf16(a, bb, oacc[c], 0, 0, 0);
            }
        }
    }

    // O -> attnb in merged [b, n, h*64+dh] bf16 layout for the output projection
    const int b = bh >> 4, h = bh & 15;
#pragma unroll
    for (int c = 0; c < 4; ++c) {
        int colg = h * 64 + c * 16 + lr;
#pragma unroll
        for (int r = 0; r < 4; ++r) {
            int n = row0 + wid * 16 + lq * 4 + r;
            attnb[(size_t)(b * SEQ + n) * D_DIM + colg] = f2b(oacc[c][r]);
        }
    }
#undef LOADK
#undef STOREK
#undef LOADV
#undef STOREV
}

// ---------------------------------------------------------------------------
extern "C" void kernel_launch(void* const* d_in, const int* in_sizes, int n_in,
                              void* d_out, int out_size, void* d_ws, size_t ws_size,
                              hipStream_t stream) {
    const float* Q = (const float*)d_in[0];
    const float* K = (const float*)d_in[1];
    const float* V = (const float*)d_in[2];
    const void* mask = d_in[3];
    const float* Wq = (const float*)d_in[4];
    const float* bq = (const float*)d_in[5];
    const float* Wk = (const float*)d_in[6];
    const float* bk = (const float*)d_in[7];
    const float* Wv = (const float*)d_in[8];
    const float* bv = (const float*)d_in[9];
    const float* Wo = (const float*)d_in[10];
    const float* bo = (const float*)d_in[11];

    char* ws = (char*)d_ws;
    int* mflag = (int*)ws;
    unsigned short* qhb = (unsigned short*)(ws + 256);     // [4,16,1024,64] bf16
    unsigned short* khb = qhb + 4194304;
    unsigned short* vhb = khb + 4194304;
    unsigned short* attnb = vhb + 4194304;                 // [4096,1024] bf16
    unsigned int* bitsbuf = (unsigned int*)(attnb + 4194304);  // 2M words = 8MB
    // total ws use: 256 + 5*8MB = ~42MB

    float* xout = (float*)d_out;                           // [4096,1024] fp32
    float* wout = xout + (size_t)BATCH * SEQ * D_DIM;      // [4,16,1024,1024] fp32

    dim3 blk(256);
    detect_mask_kernel<<<1, blk, 0, stream>>>((const uint4*)mask, mflag);
    mask_pack<<<dim3(8192), blk, 0, stream>>>(mask, mflag, bitsbuf);

    dim3 g(8, 32);  // N/128, M/128
    gemm_bt<0, 0><<<g, blk, 0, stream>>>(Q, Wq, bq, qhb);
    gemm_bt<0, 0><<<g, blk, 0, stream>>>(K, Wk, bk, khb);
    gemm_bt<0, 0><<<g, blk, 0, stream>>>(V, Wv, bv, vhb);

    attn_kernel<<<dim3(1024), blk, 0, stream>>>(qhb, khb, vhb, bitsbuf, wout, attnb);

    gemm_bt<1, 1><<<g, blk, 0, stream>>>(attnb, Wo, bo, xout);
}

// Round 2
// 645.814 us; speedup vs baseline: 1.5087x; 1.1059x over previous
//
#include <hip/hip_runtime.h>

// MHA fused forward: x = (softmax(split(QWq^T+bq) @ split(KWk^T+bk)^T / 8, mask) @ split(VWv^T+bv)) merged @ Wo^T + bo
// B=4 N=1024 D=1024 H=16 DH=64.  Outputs: x [4,1024,1024] fp32 then weights [4,16,1024,1024] fp32.

#define SEQ   1024
#define D_DIM 1024
#define HEADS 16
#define DHEAD 64
#define BATCH 4

typedef __attribute__((ext_vector_type(8))) short bhalf8;
typedef __attribute__((ext_vector_type(4))) float floatx4;

typedef __attribute__((address_space(1))) const void GlobCV;
typedef __attribute__((address_space(3))) void LdsV;

static __device__ __forceinline__ unsigned short f2b(float f) {
    // fp32 -> bf16 round-to-nearest-even (inputs are finite randoms; NaN path not needed)
    unsigned int u = __float_as_uint(f);
    u += 0x7FFFu + ((u >> 16) & 1u);
    return (unsigned short)(u >> 16);
}

static __device__ __forceinline__ void gload16(const void* g, void* l) {
    // async global->LDS, 16B per lane; LDS dest is wave-uniform base + lane*16
    __builtin_amdgcn_global_load_lds((GlobCV*)g, (LdsV*)l, 16, 0, 0);
}

// ---------------------------------------------------------------------------
// Mask dtype probe. bool mask may arrive as uint8, int32 or fp32. Byte mode
// (10% ones): P(a word is not in {0,1,0x3F800000}) ~= 0.27, so 16K words give
// miss prob 0.73^16384 ~ 0. Read 64KB as uint4, reduce, single block writes flag.
// ---------------------------------------------------------------------------
__global__ __launch_bounds__(256) void detect_mask_kernel(const uint4* __restrict__ m,
                                                          int* __restrict__ flag) {
    __shared__ int found;
    if (threadIdx.x == 0) found = 0;
    __syncthreads();
    unsigned int bad = 0;
#pragma unroll
    for (int i = 0; i < 16; ++i) {
        uint4 w = m[threadIdx.x + i * 256];  // 4096 uint4 = 64KB
        unsigned int a = w.x, b = w.y, c = w.z, d = w.w;
        bad |= (a != 0u && a != 1u && a != 0x3F800000u);
        bad |= (b != 0u && b != 1u && b != 0x3F800000u);
        bad |= (c != 0u && c != 1u && c != 0x3F800000u);
        bad |= (d != 0u && d != 1u && d != 0x3F800000u);
    }
    if (bad) atomicOr(&found, 1);
    __syncthreads();
    if (threadIdx.x == 0) *flag = found;  // 1 = byte elements, 0 = 4-byte elements
}

// ---------------------------------------------------------------------------
// Pack mask into bit array: bits[(bh*SEQ+row)*32 + col/32], bit col%32.
// ---------------------------------------------------------------------------
__global__ __launch_bounds__(256) void mask_pack(const void* __restrict__ mask,
                                                 const int* __restrict__ mflagp,
                                                 unsigned int* __restrict__ bits) {
    const size_t idx = (size_t)blockIdx.x * 256 + threadIdx.x;
    unsigned int w = 0;
    if (*mflagp) {
        const uint4* p = (const uint4*)mask + idx * 2;  // 32 bytes
        uint4 a = p[0], b = p[1];
        unsigned int d[8] = {a.x, a.y, a.z, a.w, b.x, b.y, b.z, b.w};
#pragma unroll
        for (int i = 0; i < 8; ++i) {
            unsigned int x = d[i];
            w |= (((x & 0x000000FFu) != 0u) ? 1u : 0u) << (i * 4 + 0);
            w |= (((x & 0x0000FF00u) != 0u) ? 1u : 0u) << (i * 4 + 1);
            w |= (((x & 0x00FF0000u) != 0u) ? 1u : 0u) << (i * 4 + 2);
            w |= (((x & 0xFF000000u) != 0u) ? 1u : 0u) << (i * 4 + 3);
        }
    } else {
        const uint4* p = (const uint4*)mask + idx * 8;  // 128 bytes
#pragma unroll
        for (int i = 0; i < 8; ++i) {
            uint4 a = p[i];
            w |= (a.x ? 1u : 0u) << (i * 4 + 0);
            w |= (a.y ? 1u : 0u) << (i * 4 + 1);
            w |= (a.z ? 1u : 0u) << (i * 4 + 2);
            w |= (a.w ? 1u : 0u) << (i * 4 + 3);
        }
    }
    bits[idx] = w;
}

// ---------------------------------------------------------------------------
// One-time fp32 -> bf16 casts: Q,K,V (4M elems each) -> Ab[z], Wq/Wk/Wv/Wo
// (1M each) -> Wb[z]. Removes all conversion VALU from the GEMM hot loops and
// enables global_load_lds staging. Each thread: 8 elems (2x float4 -> 2x ushort4).
// ---------------------------------------------------------------------------
__global__ __launch_bounds__(256) void cast_f2b_all(const float* __restrict__ Q,
                                                    const float* __restrict__ K,
                                                    const float* __restrict__ V,
                                                    const float* __restrict__ Wq,
                                                    const float* __restrict__ Wk,
                                                    const float* __restrict__ Wv,
                                                    const float* __restrict__ Wo,
                                                    unsigned short* __restrict__ Ab,
                                                    unsigned short* __restrict__ Wb) {
    const int y = blockIdx.y;
    const float* src;
    unsigned short* dst;
    int nblocks;
    if (y < 3) {
        src = (y == 0) ? Q : (y == 1) ? K : V;
        dst = Ab + ((size_t)y << 22);
        nblocks = 2048;
    } else {
        src = (y == 3) ? Wq : (y == 4) ? Wk : (y == 5) ? Wv : Wo;
        dst = Wb + ((size_t)(y - 3) << 20);
        nblocks = 512;
    }
    if (blockIdx.x >= (unsigned)nblocks) return;
    const size_t i = ((size_t)blockIdx.x * 256 + threadIdx.x) * 8;
    float4 f0 = *(const float4*)&src[i];
    float4 f1 = *(const float4*)&src[i + 4];
    ushort4 h0, h1;
    h0.x = f2b(f0.x); h0.y = f2b(f0.y); h0.z = f2b(f0.z); h0.w = f2b(f0.w);
    h1.x = f2b(f1.x); h1.y = f2b(f1.y); h1.z = f2b(f1.z); h1.w = f2b(f1.w);
    *(ushort4*)&dst[i] = h0;
    *(ushort4*)&dst[i + 4] = h1;
}

// ---------------------------------------------------------------------------
// GEMM (m97 structure): Out[m,n] = sum_k A[m,k]*W[n,k] + bias[n], all-bf16 inputs.
// 128x128 tile, BK=64, 4 waves (2x2), 4x4 MFMA frags/wave. Staging is pure
// global_load_lds width=16 into LINEAR LDS tiles [128][64] (no conversion, no
// staging VGPRs). blockIdx.z batches independent GEMMs (QKV: z=0..2) so the
// grid is 768 blocks = 3 blocks/CU (m97's occupancy sweet spot).
// OMODE 0: write bf16 scattered to [b,h,n,dh] (+bias); OMODE 1: fp32 row-major.
// ---------------------------------------------------------------------------
template <int OMODE>
__global__ __launch_bounds__(256) void gemm_lds(const unsigned short* __restrict__ Abase,
                                                const unsigned short* __restrict__ Wbase,
                                                const float* __restrict__ b0,
                                                const float* __restrict__ b1,
                                                const float* __restrict__ b2,
                                                void* __restrict__ Obase) {
    __shared__ unsigned short Al[128 * 64];  // linear: required by global_load_lds
    __shared__ unsigned short Bl[128 * 64];

    const int tid = threadIdx.x;
    const int lane = tid & 63, wid = tid >> 6;
    const int lr = lane & 15, lq = lane >> 4;
    const int wm = (wid & 1) * 64, wn = (wid >> 1) * 64;
    const int rowBase = blockIdx.y * 128;
    const int colBase = blockIdx.x * 128;
    const int z = blockIdx.z;

    const unsigned short* A = Abase + ((size_t)z << 22);  // [4096,1024] per z
    const unsigned short* W = Wbase + ((size_t)z << 20);  // [1024,1024] per z
    const float* bias = (z == 0) ? b0 : (z == 1) ? b1 : b2;

    // per-lane source position within an 8-row x 64-col (1KB) chunk
    const int srow = lane >> 3;
    const int scol = (lane & 7) * 8;

    floatx4 acc[4][4];
#pragma unroll
    for (int mi = 0; mi < 4; ++mi)
#pragma unroll
        for (int ni = 0; ni < 4; ++ni)
#pragma unroll
            for (int r = 0; r < 4; ++r) acc[mi][ni][r] = 0.f;

    for (int k0 = 0; k0 < D_DIM; k0 += 64) {
        // stage A-tile: 16 chunks of 8 rows; wave w owns chunks w*4..w*4+3
#pragma unroll
        for (int i = 0; i < 4; ++i) {
            int chunk = wid * 4 + i;
            gload16(&A[(size_t)(rowBase + chunk * 8 + srow) * D_DIM + k0 + scol],
                    &Al[chunk * 512]);
        }
#pragma unroll
        for (int i = 0; i < 4; ++i) {
            int chunk = wid * 4 + i;
            gload16(&W[(size_t)(colBase + chunk * 8 + srow) * D_DIM + k0 + scol],
                    &Bl[chunk * 512]);
        }
        __syncthreads();  // compiler drains vmcnt before s_barrier
#pragma unroll
        for (int ks = 0; ks < 2; ++ks) {
            bhalf8 af[4], bfr[4];
#pragma unroll
            for (int mi = 0; mi < 4; ++mi)
                af[mi] = *(const bhalf8*)&Al[(wm + mi * 16 + lr) * 64 + ks * 32 + lq * 8];
#pragma unroll
            for (int ni = 0; ni < 4; ++ni)
                bfr[ni] = *(const bhalf8*)&Bl[(wn + ni * 16 + lr) * 64 + ks * 32 + lq * 8];
#pragma unroll
            for (int mi = 0; mi < 4; ++mi)
#pragma unroll
                for (int ni = 0; ni < 4; ++ni)
                    acc[mi][ni] = __builtin_amdgcn_mfma_f32_16x16x32_bf16(af[mi], bfr[ni],
                                                                          acc[mi][ni], 0, 0, 0);
        }
        __syncthreads();
    }

    // Epilogue. C/D layout (verified m89/m91): col = lane&15, row = (lane>>4)*4 + reg.
#pragma unroll
    for (int mi = 0; mi < 4; ++mi) {
#pragma unroll
        for (int ni = 0; ni < 4; ++ni) {
            int col = colBase + wn + ni * 16 + lr;
            float bv = bias[col];
#pragma unroll
            for (int r = 0; r < 4; ++r) {
                int m = rowBase + wm + mi * 16 + lq * 4 + r;
                float v = acc[mi][ni][r] + bv;
                if (OMODE == 0) {
                    unsigned short* o = (unsigned short*)Obase + ((size_t)z << 22);
                    int b = m >> 10, n = m & 1023, h = col >> 6, dh = col & 63;
                    o[(((size_t)(b * HEADS + h)) << 16) + (n << 6) + dh] = f2b(v);
                } else {
                    float* o = (float*)Obase;
                    o[(size_t)m * D_DIM + col] = v;
                }
            }
        }
    }
}

// ---------------------------------------------------------------------------
// Attention: one block = one (b,h) and a 64-row q tile. Two-pass softmax,
// latency-hiding structure (unchanged from previous round, verified):
//  - mask bits staged once per block from the packed bit array
//  - per-LANE online (m,l) in pass 1; single cross-lane merge at the end
//  - K (and V in pass 2) prefetched into registers one tile ahead (T14)
//  - XOR-swizzled unpadded LDS tiles; 40KB LDS -> 4 blocks/CU
//  - XCD-grouped block decode for K/V L2 locality
// ---------------------------------------------------------------------------
__global__ __launch_bounds__(256, 4) void attn_kernel(const unsigned short* __restrict__ qh,
                                                      const unsigned short* __restrict__ kh,
                                                      const unsigned short* __restrict__ vh,
                                                      const unsigned int* __restrict__ bits,
                                                      float* __restrict__ wout,
                                                      unsigned short* __restrict__ attnb) {
    __shared__ unsigned short ql[64 * 64];
    __shared__ unsigned short kl[64 * 64];
    __shared__ unsigned short vtl[64 * 64];
    __shared__ unsigned short pl[64 * 64];
    __shared__ unsigned int maskw[64 * 32];  // 64 rows x 1024 bits

    const int tid = threadIdx.x;
    const int lane = tid & 63, wid = tid >> 6;
    const int lr = lane & 15, lq = lane >> 4;

    const int wg = blockIdx.x;
    const int xcd = wg & 7, tt = wg >> 3;
    const int bh = ((tt >> 4) << 3) | xcd;   // 0..63
    const int row0 = (tt & 15) << 6;

    const size_t hoff = (size_t)bh << 16;  // *SEQ*DHEAD
    const unsigned short* qp = qh + hoff;
    const unsigned short* kp = kh + hoff;
    const unsigned short* vp = vh + hoff;

    // ---- one-time staging: q tile (swizzled) + mask bits (8KB, coalesced) ----
#pragma unroll
    for (int i = 0; i < 2; ++i) {
        int id = tid + i * 256;
        int r = id >> 3, c8 = id & 7;
        *(uint4*)&ql[r * 64 + ((c8 ^ (r & 7)) << 3)] =
            *(const uint4*)&qp[((size_t)(row0 + r) << 6) + c8 * 8];
    }
    {
        const unsigned int* src = bits + ((size_t)bh * SEQ + row0) * 32;
#pragma unroll
        for (int i = 0; i < 2; ++i) {
            int id = tid + i * 256;  // 512 uint4 = 2048 words
            *(uint4*)&maskw[id * 4] = *(const uint4*)&src[id * 4];
        }
    }

    uint4 kreg0, kreg1, vreg0, vreg1;
#define LOADK(j)                                                                          \
    {                                                                                     \
        kreg0 = *(const uint4*)&kp[((size_t)(((j) << 6) + (tid >> 3)) << 6) + (tid & 7) * 8];        \
        kreg1 = *(const uint4*)&kp[((size_t)(((j) << 6) + ((tid + 256) >> 3)) << 6) + (tid & 7) * 8]; \
    }
#define STOREK                                                                  \
    {                                                                           \
        int r0 = tid >> 3, c0 = tid & 7, r1 = (tid + 256) >> 3;                 \
        *(uint4*)&kl[r0 * 64 + ((c0 ^ (r0 & 7)) << 3)] = kreg0;                 \
        *(uint4*)&kl[r1 * 64 + ((c0 ^ (r1 & 7)) << 3)] = kreg1;                 \
    }
#define LOADV(j)                                                                          \
    {                                                                                     \
        vreg0 = *(const uint4*)&vp[((size_t)(((j) << 6) + (tid & 63)) << 6) + ((tid >> 6) * 8)];      \
        vreg1 = *(const uint4*)&vp[((size_t)(((j) << 6) + (tid & 63)) << 6) + ((tid >> 6) * 8 + 32)]; \
    }
#define STOREV                                                                  \
    {                                                                           \
        int n0 = tid & 63, d0 = (tid >> 6) * 8, d1 = d0 + 32;                   \
        const unsigned short* e0 = (const unsigned short*)&vreg0;               \
        const unsigned short* e1 = (const unsigned short*)&vreg1;               \
        _Pragma("unroll") for (int t = 0; t < 8; ++t) {                         \
            vtl[(d0 + t) * 64 + (n0 ^ (t << 3))] = e0[t];                       \
            vtl[(d1 + t) * 64 + (n0 ^ (t << 3))] = e1[t];                       \
        }                                                                       \
    }

    // ---- pass 1: per-lane online (m,l); merge across lanes once at the end ----
    float m_l[4], l_l[4];
#pragma unroll
    for (int r = 0; r < 4; ++r) { m_l[r] = -3e38f; l_l[r] = 0.f; }

    LOADK(0);
    for (int j = 0; j < 16; ++j) {
        __syncthreads();           // prior iter's kl reads done
        STOREK;
        if (j < 15) LOADK(j + 1);  // prefetch hides HBM/L2 latency under compute
        __syncthreads();

        floatx4 sacc[4];
#pragma unroll
        for (int c = 0; c < 4; ++c)
#pragma unroll
            for (int r = 0; r < 4; ++r) sacc[c][r] = 0.f;
#pragma unroll
        for (int ks = 0; ks < 2; ++ks) {
            int arow = wid * 16 + lr;
            bhalf8 a = *(const bhalf8*)&ql[arow * 64 + (((ks * 4 + lq) ^ (lr & 7)) << 3)];
#pragma unroll
            for (int c = 0; c < 4; ++c) {
                int brow = c * 16 + lr;
                bhalf8 bb = *(const bhalf8*)&kl[brow * 64 + (((ks * 4 + lq) ^ (lr & 7)) << 3)];
                sacc[c] = __builtin_amdgcn_mfma_f32_16x16x32_bf16(a, bb, sacc[c], 0, 0, 0);
            }
        }
        unsigned int w0[4], w1[4];
#pragma unroll
        for (int r = 0; r < 4; ++r) {
            int row = wid * 16 + lq * 4 + r;
            w0[r] = maskw[row * 32 + j * 2];
            w1[r] = maskw[row * 32 + j * 2 + 1];
        }
#pragma unroll
        for (int c = 0; c < 4; ++c) {
            int sh = lr + ((c & 1) << 4);
#pragma unroll
            for (int r = 0; r < 4; ++r) {
                unsigned int w = (c >> 1) ? w1[r] : w0[r];
                float s = sacc[c][r] * 0.125f;  // /sqrt(64)
                sacc[c][r] = ((w >> sh) & 1u) ? -1e10f : s;
            }
        }
#pragma unroll
        for (int r = 0; r < 4; ++r) {
            float mx = fmaxf(fmaxf(sacc[0][r], sacc[1][r]), fmaxf(sacc[2][r], sacc[3][r]));
            float mn = fmaxf(m_l[r], mx);
            float sv = __expf(sacc[0][r] - mn) + __expf(sacc[1][r] - mn) +
                       __expf(sacc[2][r] - mn) + __expf(sacc[3][r] - mn);
            l_l[r] = l_l[r] * __expf(m_l[r] - mn) + sv;
            m_l[r] = mn;
        }
    }
    // merge (m,l) across the 16 lanes sharing each row
#pragma unroll
    for (int o = 1; o < 16; o <<= 1) {
#pragma unroll
        for (int r = 0; r < 4; ++r) {
            float mo = __shfl_xor(m_l[r], o);
            float lo = __shfl_xor(l_l[r], o);
            float mn = fmaxf(m_l[r], mo);
            l_l[r] = l_l[r] * __expf(m_l[r] - mn) + lo * __expf(mo - mn);
            m_l[r] = mn;
        }
    }
    float invl[4];
#pragma unroll
    for (int r = 0; r < 4; ++r) invl[r] = 1.f / l_l[r];

    // ---- pass 2: weights out + P@V (recompute S; K/V prefetched) ----
    floatx4 oacc[4];
#pragma unroll
    for (int c = 0; c < 4; ++c)
#pragma unroll
        for (int r = 0; r < 4; ++r) oacc[c][r] = 0.f;
    const size_t wrowbase = ((size_t)bh * SEQ + row0) * SEQ;

    LOADK(0);
    LOADV(0);
    for (int j = 0; j < 16; ++j) {
        __syncthreads();
        STOREK;
        STOREV;
        if (j < 15) { LOADK(j + 1); LOADV(j + 1); }
        __syncthreads();

        floatx4 sacc[4];
#pragma unroll
        for (int c = 0; c < 4; ++c)
#pragma unroll
            for (int r = 0; r < 4; ++r) sacc[c][r] = 0.f;
#pragma unroll
        for (int ks = 0; ks < 2; ++ks) {
            int arow = wid * 16 + lr;
            bhalf8 a = *(const bhalf8*)&ql[arow * 64 + (((ks * 4 + lq) ^ (lr & 7)) << 3)];
#pragma unroll
            for (int c = 0; c < 4; ++c) {
                int brow = c * 16 + lr;
                bhalf8 bb = *(const bhalf8*)&kl[brow * 64 + (((ks * 4 + lq) ^ (lr & 7)) << 3)];
                sacc[c] = __builtin_amdgcn_mfma_f32_16x16x32_bf16(a, bb, sacc[c], 0, 0, 0);
            }
        }
        unsigned int w0[4], w1[4];
#pragma unroll
        for (int r = 0; r < 4; ++r) {
            int row = wid * 16 + lq * 4 + r;
            w0[r] = maskw[row * 32 + j * 2];
            w1[r] = maskw[row * 32 + j * 2 + 1];
        }
#pragma unroll
        for (int c = 0; c < 4; ++c) {
            int sh = lr + ((c & 1) << 4);
            int col = (j << 6) + c * 16 + lr;
#pragma unroll
            for (int r = 0; r < 4; ++r) {
                unsigned int w = (c >> 1) ? w1[r] : w0[r];
                int row = wid * 16 + lq * 4 + r;
                float s = sacc[c][r] * 0.125f;
                if ((w >> sh) & 1u) s = -1e10f;
                float p = __expf(s - m_l[r]) * invl[r];
                wout[wrowbase + (size_t)row * SEQ + col] = p;
                pl[row * 64 + ((c * 16 + lr) ^ ((row & 7) << 3))] = f2b(p);
            }
        }
#pragma unroll
        for (int ks = 0; ks < 2; ++ks) {
            int arow = wid * 16 + lr;
            bhalf8 a = *(const bhalf8*)&pl[arow * 64 + (((ks * 4 + lq) ^ (lr & 7)) << 3)];
#pragma unroll
            for (int c = 0; c < 4; ++c) {
                int brow = c * 16 + lr;
                bhalf8 bb = *(const bhalf8*)&vtl[brow * 64 + (((ks * 4 + lq) ^ (lr & 7)) << 3)];
                oacc[c] = __builtin_amdgcn_mfma_f32_16x16x32_bf16(a, bb, oacc[c], 0, 0, 0);
            }
        }
    }

    // O -> attnb in merged [b, n, h*64+dh] bf16 layout for the output projection
    const int b = bh >> 4, h = bh & 15;
#pragma unroll
    for (int c = 0; c < 4; ++c) {
        int colg = h * 64 + c * 16 + lr;
#pragma unroll
        for (int r = 0; r < 4; ++r) {
            int n = row0 + wid * 16 + lq * 4 + r;
            attnb[(size_t)(b * SEQ + n) * D_DIM + colg] = f2b(oacc[c][r]);
        }
    }
#undef LOADK
#undef STOREK
#undef LOADV
#undef STOREV
}

// ---------------------------------------------------------------------------
extern "C" void kernel_launch(void* const* d_in, const int* in_sizes, int n_in,
                              void* d_out, int out_size, void* d_ws, size_t ws_size,
                              hipStream_t stream) {
    const float* Q = (const float*)d_in[0];
    const float* K = (const float*)d_in[1];
    const float* V = (const float*)d_in[2];
    const void* mask = d_in[3];
    const float* Wq = (const float*)d_in[4];
    const float* bq = (const float*)d_in[5];
    const float* Wk = (const float*)d_in[6];
    const float* bk = (const float*)d_in[7];
    const float* Wv = (const float*)d_in[8];
    const float* bv = (const float*)d_in[9];
    const float* Wo = (const float*)d_in[10];
    const float* bo = (const float*)d_in[11];

    char* ws = (char*)d_ws;
    int* mflag = (int*)ws;
    unsigned short* qhb = (unsigned short*)(ws + 256);     // [4,16,1024,64] bf16 x3 contiguous
    unsigned short* khb = qhb + 4194304;
    unsigned short* vhb = khb + 4194304;
    unsigned short* attnb = vhb + 4194304;                 // [4096,1024] bf16
    unsigned int* bitsbuf = (unsigned int*)(attnb + 4194304);  // 2M words = 8MB
    unsigned short* Wbf = (unsigned short*)(bitsbuf + 2097152); // 4x[1024,1024] bf16 = 8MB
    // ws use: 256 + 24MB + 8MB + 8MB + 8MB = ~48.3MB

    // Q/K/V bf16 scratch (24MB) lives in the d_out TAIL: it is consumed by the
    // QKV GEMM, which completes before attn_kernel overwrites wout. attn then
    // rewrites every element of that region with the real weights output.
    unsigned short* Abf =
        (unsigned short*)((char*)d_out + (size_t)out_size - (size_t)3 * 4194304 * 2);

    float* xout = (float*)d_out;                           // [4096,1024] fp32
    float* wout = xout + (size_t)BATCH * SEQ * D_DIM;      // [4,16,1024,1024] fp32

    dim3 blk(256);
    detect_mask_kernel<<<1, blk, 0, stream>>>((const uint4*)mask, mflag);
    mask_pack<<<dim3(8192), blk, 0, stream>>>(mask, mflag, bitsbuf);
    cast_f2b_all<<<dim3(2048, 7), blk, 0, stream>>>(Q, K, V, Wq, Wk, Wv, Wo, Abf, Wbf);

    // QKV projections: one batched dispatch, 8x32x3 = 768 blocks = 3 blocks/CU
    gemm_lds<0><<<dim3(8, 32, 3), blk, 0, stream>>>(Abf, Wbf, bq, bk, bv, qhb);

    attn_kernel<<<dim3(1024), blk, 0, stream>>>(qhb, khb, vhb, bitsbuf, wout, attnb);

    // output projection
    gemm_lds<1><<<dim3(8, 32, 1), blk, 0, stream>>>(attnb, Wbf + 3 * 1048576, bo, bo, bo, xout);
}